// Round 8
// baseline (681.178 us; speedup 1.0000x reference)
//
#include <hip/hip_runtime.h>
#include <hip/hip_cooperative_groups.h>
#include <cstdint>
#include <cstddef>

namespace cg = cooperative_groups;

#define BATCH 16
#define NCLS 80
#define NANCH 25200          // (80*80 + 40*40 + 20*20) * 3
#define G 48                 // anchors per chunk
#define NCHUNK 525           // chunks per image
#define TOTCH (BATCH * NCHUNK)   // 8400
#define NBLK 256
#define NTHR 1024
#define CPB 4                // chunks per block in fallback k_max
#define ABINS 512
#define SBINS 1024
#define CAP 2048
#define TILE 64
#define KC 300
#define DET 100
#define SCORE_T 0.25f
#define NMS_T 0.45f
#define SLICE (NANCH / 16)   // 1575

typedef unsigned long long ull;

__device__ __forceinline__ float sg(float x) { return 1.0f / (1.0f + expf(-x)); }

__device__ __forceinline__ const float* anchor_base(const float* p3, const float* p4,
                                                    const float* p5, int b, int n) {
    if (n < 19200) return p3 + ((size_t)b * 19200 + n) * 85;
    if (n < 24000) return p4 + ((size_t)b * 4800 + (n - 19200)) * 85;
    return p5 + ((size_t)b * 1200 + (n - 24000)) * 85;
}

struct Chunk { const float4* p; int outbase; };
__device__ __forceinline__ Chunk chunk_of(int g, const float* p3, const float* p4,
                                          const float* p5) {
    Chunk ck;
    int b = g / NCHUNK, ch = g % NCHUNK;
    const float* src; int a0, lvlN, gbase;
    if (ch < 400)      { src = p3; a0 = ch * G;         lvlN = 19200; gbase = 0; }
    else if (ch < 500) { src = p4; a0 = (ch - 400) * G; lvlN = 4800;  gbase = 19200; }
    else               { src = p5; a0 = (ch - 500) * G; lvlN = 1200;  gbase = 24000; }
    ck.p = (const float4*)(src + ((size_t)b * lvlN + a0) * 85);
    ck.outbase = b * NANCH + gbase + a0;
    return ck;
}

// ======================= cooperative single-kernel path =======================
__global__ __launch_bounds__(1024) void k_all(
    const float* __restrict__ p3, const float* __restrict__ p4, const float* __restrict__ p5,
    const float* __restrict__ anchors, const int* __restrict__ imshapes,
    const float* __restrict__ scalef,
    float* __restrict__ gmax, unsigned int* __restrict__ shist,
    unsigned int* __restrict__ acnt, unsigned int* __restrict__ scnt,
    int* __restrict__ alist, uint2* __restrict__ cand, float* __restrict__ out) {
    __shared__ __align__(16) unsigned char smem[40960];
    __shared__ int TaS, TsS;
    cg::grid_group grid = cg::this_grid();
    int tid = threadIdx.x;

    // ---- P1: zero ws counters + stream predictions -> gmax ----
    {
        int gid = blockIdx.x * NTHR + tid;
        int zn = BATCH * SBINS + 2 * BATCH;   // shist + acnt + scnt (contiguous)
        for (int i = gid; i < zn; i += NBLK * NTHR) shist[i] = 0u;

        float* buf = (float*)smem;                 // 4080 floats
        float* pmax = (float*)(smem + 16320);      // 240 floats
        Chunk cur = chunk_of(blockIdx.x, p3, p4, p5);
        float4 pre = (tid < 1020) ? cur.p[tid] : make_float4(0.f, 0.f, 0.f, 0.f);
        for (int k = 0; k < 33; k++) {
            int g = blockIdx.x + NBLK * k;
            if (g >= TOTCH) break;
            if (tid < 1020) ((float4*)buf)[tid] = pre;
            int gn = g + NBLK;
            Chunk nxt = cur;
            if (gn < TOTCH) {
                nxt = chunk_of(gn, p3, p4, p5);
                if (tid < 1020) pre = nxt.p[tid];
            }
            __syncthreads();
            if (tid < 240) {                       // 48 anchors x 5 parts of 16 classes
                int a = tid % G, part = tid / G;
                const float* base = buf + a * 85 + 5 + part * 16;
                float m = base[0];
#pragma unroll
                for (int q = 1; q < 16; q++) m = fmaxf(m, base[q]);
                pmax[part * G + a] = m;
            }
            __syncthreads();
            if (tid < G) {
                float m = pmax[tid];
#pragma unroll
                for (int p = 1; p < 5; p++) m = fmaxf(m, pmax[p * G + tid]);
                float obj = sg(buf[tid * 85 + 4]);
                float v = 0.0f;
                if (obj > SCORE_T) v = obj * sg(m);   // sigma monotone => true max score
                gmax[cur.outbase + tid] = v;
            }
            __syncthreads();
            cur = nxt;
        }
    }
    __threadfence();
    grid.sync();

    // ---- P2: per-image anchor threshold Ta (redundant x16) + collect ----
    {
        int b = blockIdx.x >> 4, sub = blockIdx.x & 15;
        unsigned int* hist = (unsigned int*)smem;
        if (tid < ABINS) hist[tid] = 0u;
        if (tid == 0) TaS = 0;
        __syncthreads();
        const float* gm = gmax + (size_t)b * NANCH;
        for (int n = tid; n < NANCH; n += NTHR) {
            float v = gm[n];
            if (v > SCORE_T) {
                int bin = (int)((v - SCORE_T) * (ABINS / 0.75f));
                bin = bin < 0 ? 0 : (bin > ABINS - 1 ? ABINS - 1 : bin);
                atomicAdd(&hist[bin], 1u);
            }
        }
        __syncthreads();
        unsigned int run = (tid < ABINS) ? hist[tid] : 0u;
        __syncthreads();
        for (int off = 1; off < ABINS; off <<= 1) {
            unsigned int add = (tid < ABINS && tid + off < ABINS) ? hist[tid + off] : 0u;
            __syncthreads();
            if (tid < ABINS) { run += add; hist[tid] = run; }
            __syncthreads();
        }
        if (tid < ABINS && run >= KC && (tid == ABINS - 1 || hist[tid + 1] < KC)) TaS = tid;
        __syncthreads();
        int Ta = TaS;
        for (int n = sub * SLICE + tid; n < (sub + 1) * SLICE; n += NTHR) {
            float v = gm[n];
            if (v > SCORE_T) {
                int bin = (int)((v - SCORE_T) * (ABINS / 0.75f));
                bin = bin < 0 ? 0 : (bin > ABINS - 1 ? ABINS - 1 : bin);
                if (bin >= Ta) {
                    unsigned int pos = atomicAdd(&acnt[b], 1u);
                    if (pos < CAP) alist[b * CAP + pos] = n;
                }
            }
        }
    }
    __threadfence();
    grid.sync();

    // ---- P3: score histogram over candidate anchors ----
    {
        int b = blockIdx.x >> 4, sub = blockIdx.x & 15;
        unsigned int* hist = (unsigned int*)smem;
        hist[tid] = 0u;                            // SBINS == NTHR
        __syncthreads();
        int M = (int)acnt[b]; if (M > CAP) M = CAP;
        int Mb = (M > sub) ? (M - sub + 15) / 16 : 0;
        for (int w = tid; w < Mb * NCLS; w += NTHR) {
            int t = w / NCLS, c = w - t * NCLS;
            int n = alist[b * CAP + sub + 16 * t];
            const float* base = anchor_base(p3, p4, p5, b, n);
            float s = sg(base[4]) * sg(base[5 + c]);
            if (s > SCORE_T) {
                int bin = (int)((s - SCORE_T) * (SBINS / 0.75f));
                bin = bin < 0 ? 0 : (bin > SBINS - 1 ? SBINS - 1 : bin);
                atomicAdd(&hist[bin], 1u);
            }
        }
        __syncthreads();
        if (hist[tid]) atomicAdd(&shist[b * SBINS + tid], hist[tid]);
    }
    __threadfence();
    grid.sync();

    // ---- P4: score threshold Ts (redundant x16) + collect candidates ----
    {
        int b = blockIdx.x >> 4, sub = blockIdx.x & 15;
        unsigned int* hist = (unsigned int*)smem;
        unsigned int run = shist[b * SBINS + tid];
        if (tid == 0) TsS = 0;
        hist[tid] = run;
        __syncthreads();
        for (int off = 1; off < SBINS; off <<= 1) {
            unsigned int add = (tid + off < SBINS) ? hist[tid + off] : 0u;
            __syncthreads();
            run += add;
            hist[tid] = run;
            __syncthreads();
        }
        if (run >= KC && (tid == SBINS - 1 || hist[tid + 1] < KC)) TsS = tid;
        __syncthreads();
        int Ts = TsS;
        int M = (int)acnt[b]; if (M > CAP) M = CAP;
        int Mb = (M > sub) ? (M - sub + 15) / 16 : 0;
        for (int w = tid; w < Mb * NCLS; w += NTHR) {
            int t = w / NCLS, c = w - t * NCLS;
            int n = alist[b * CAP + sub + 16 * t];
            const float* base = anchor_base(p3, p4, p5, b, n);
            float s = sg(base[4]) * sg(base[5 + c]);   // identical expr to P3
            if (s > SCORE_T) {
                int bin = (int)((s - SCORE_T) * (SBINS / 0.75f));
                bin = bin < 0 ? 0 : (bin > SBINS - 1 ? SBINS - 1 : bin);
                if (bin >= Ts) {
                    unsigned int pos = atomicAdd(&scnt[b], 1u);
                    if (pos < CAP)
                        cand[(size_t)b * CAP + pos] =
                            make_uint2(__float_as_uint(s), (unsigned int)(n * NCLS + c));
                }
            }
        }
    }
    __threadfence();
    grid.sync();

    // ---- P5: per-image rank-select top-300, decode, NMS, output ----
    if (blockIdx.x >= BATCH) return;
    {
        int b = blockIdx.x;
        float*        cs    = (float*)smem;                    // [2048]
        unsigned int* ci    = (unsigned int*)(smem + 8192);    // [2048]
        ull*          msk   = (ull*)(smem + 16384);            // [1500]
        float4*       bx    = (float4*)(smem + 28384);         // [300]
        int*          lab   = (int*)(smem + 33184);
        float*        sc2   = (float*)(smem + 34384);
        float*        ar    = (float*)(smem + 35584);
        float*        sv    = (float*)(smem + 36784);
        unsigned int* si    = (unsigned int*)(smem + 37984);
        ull*          keep  = (ull*)(smem + 39184);            // [5]
        unsigned int* actw  = (unsigned int*)(smem + 39224);   // [10]
        int*          wpref = (int*)(smem + 39264);            // [6]
        int*          order = (int*)(smem + 39288);            // [100]
        int*          okept = (int*)(smem + 39688);            // [100]

        int nc = (int)scnt[b];
        if (nc > CAP) nc = CAP;
        for (int i = tid; i < nc; i += NTHR) {
            uint2 cc = cand[(size_t)b * CAP + i];
            cs[i] = __uint_as_float(cc.x);
            ci[i] = cc.y;
        }
        if (tid < KC) { sv[tid] = 0.f; si[tid] = 0xffffffffu; }
        if (tid < 10) actw[tid] = 0u;
        __syncthreads();

        for (int i = tid; i < nc; i += NTHR) {     // rank-select (score desc, idx asc)
            float s = cs[i];
            unsigned int ii = ci[i];
            int r = 0;
            for (int j = 0; j < nc; j++) {
                float sj = cs[j];
                unsigned int ij = ci[j];
                if (sj > s || (sj == s && ij < ii)) r++;
            }
            if (r < KC) { sv[r] = s; si[r] = ii; }
        }
        __syncthreads();
        int valid = nc < KC ? nc : KC;

        if (tid < KC) {                             // decode
            int i = tid;
            if (i < valid) {
                unsigned int fi = si[i];
                int n = (int)(fi / NCLS), c = (int)(fi % NCLS);
                int lvl = (n < 19200) ? 0 : (n < 24000 ? 1 : 2);
                const int offl[3] = {0, 19200, 24000};
                const int Wl[3] = {80, 40, 20};
                const int cntl[3] = {19200, 4800, 1200};
                const float strl[3] = {8.f, 16.f, 32.f};
                const float* pp = lvl == 0 ? p3 : (lvl == 1 ? p4 : p5);
                int nl = n - offl[lvl];
                int a = nl % 3, cell = nl / 3;
                int gx = cell % Wl[lvl], gy = cell / Wl[lvl];
                const float* pb = pp + ((size_t)b * cntl[lvl] + nl) * 85;
                float s0 = sg(pb[0]), s1 = sg(pb[1]), s2 = sg(pb[2]), s3 = sg(pb[3]);
                float stride = strl[lvl];
                float aw = anchors[(lvl * 3 + a) * 2 + 0];
                float ah = anchors[(lvl * 3 + a) * 2 + 1];
                float cx = (2.0f * s0 - 0.5f + (float)gx) * stride;
                float cy = (2.0f * s1 - 0.5f + (float)gy) * stride;
                float bw = 4.0f * s2 * s2 * aw;
                float bh = 4.0f * s3 * s3 * ah;
                float hf = (float)imshapes[b * 2 + 0];
                float wf = (float)imshapes[b * 2 + 1];
                float x1 = cx - bw / 2.0f, y1 = cy - bh / 2.0f;
                float x2 = cx + bw / 2.0f, y2 = cy + bh / 2.0f;
                x1 = fminf(fmaxf(x1, 0.f), wf);
                y1 = fminf(fmaxf(y1, 0.f), hf);
                x2 = fminf(fmaxf(x2, 0.f), wf);
                y2 = fminf(fmaxf(y2, 0.f), hf);
                bx[i] = make_float4(x1, y1, x2, y2);
                lab[i] = c;
                sc2[i] = sv[i];
                ar[i] = (x2 - x1) * (y2 - y1);
            } else {
                bx[i] = make_float4(0, 0, 0, 0);
                lab[i] = -1 - i;
                sc2[i] = 0.f;
                ar[i] = 0.f;
            }
        }
        __syncthreads();

        for (int t = tid; t < KC * 5; t += NTHR) {  // suppression bitmask
            int i = t / 5, w = t % 5;
            float4 bi = bx[i];
            int li = lab[i];
            float ai = ar[i];
            ull m = 0ull;
            for (int tb = 0; tb < 64; tb++) {
                int j = w * 64 + tb;
                if (j < KC && j > i && lab[j] == li) {
                    float4 bj = bx[j];
                    float ltx = fmaxf(bi.x, bj.x), lty = fmaxf(bi.y, bj.y);
                    float rbx = fminf(bi.z, bj.z), rby = fminf(bi.w, bj.w);
                    float iw = fmaxf(rbx - ltx, 0.f), ih = fmaxf(rby - lty, 0.f);
                    float inter = iw * ih;
                    float iou = inter / (ai + ar[j] - inter + 1e-9f);
                    if (iou > NMS_T) m |= (1ull << tb);
                }
            }
            msk[t] = m;
        }
        __syncthreads();

        for (int i = tid; i < KC; i += NTHR) {      // active rows
            ull nz = msk[i * 5] | msk[i * 5 + 1] | msk[i * 5 + 2] |
                     msk[i * 5 + 3] | msk[i * 5 + 4];
            if (nz) atomicOr(&actw[i >> 5], 1u << (i & 31));
        }
        __syncthreads();
        if (tid == 0) {
            keep[0] = keep[1] = keep[2] = keep[3] = keep[4] = ~0ull;
            for (int w = 0; w < 10; w++) {
                unsigned int mw = actw[w];
                while (mw) {
                    int bpos = __ffs(mw) - 1;
                    mw &= mw - 1;
                    int i = w * 32 + bpos;
                    if ((keep[i >> 6] >> (i & 63)) & 1ull) {
#pragma unroll
                        for (int r = 0; r < 5; r++) keep[r] &= ~msk[i * 5 + r];
                    }
                }
            }
            int s = 0;
            for (int w = 0; w < 5; w++) {
                ull kw = keep[w];
                if (w == 4) kw &= (1ull << 44) - 1ull;
                wpref[w] = s;
                s += (int)__popcll(kw);
            }
            wpref[5] = s;
        }
        __syncthreads();

        if (tid < KC) {
            int w = tid >> 6, bp = tid & 63;
            ull kw = keep[w];
            bool kept = (kw >> bp) & 1ull;
            int r = wpref[w] + (int)__popcll(kw & ((1ull << bp) - 1ull));
            if (kept) {
                if (r < DET) { order[r] = tid; okept[r] = 1; }
            } else {
                int nr = wpref[5] + (tid - r);
                if (nr < DET) { order[nr] = tid; okept[nr] = 0; }
            }
        }
        __syncthreads();

        if (tid < DET) {
            int o = order[tid];
            float scale = scalef[b];
            float4 bb = bx[o];
            float s = (okept[tid] && o < valid) ? sc2[o] : 0.f;
            float lb = (o < valid) ? (float)lab[o] : 0.f;
            float* po = out + ((size_t)b * DET + tid) * 6;
            po[0] = bb.x / scale;
            po[1] = bb.y / scale;
            po[2] = bb.z / scale;
            po[3] = bb.w / scale;
            po[4] = s;
            po[5] = lb;
        }
    }
}

// ======================= fallback two-kernel path (R6, proven) =======================
__global__ __launch_bounds__(256) void k_max(const float* __restrict__ p3,
                                             const float* __restrict__ p4,
                                             const float* __restrict__ p5,
                                             float* __restrict__ gmax) {
    __shared__ __align__(16) float buf[G * 85];
    __shared__ float pmax[5 * G];
    int tid = threadIdx.x;
    int g0 = blockIdx.x * CPB;
    Chunk cur = chunk_of(g0, p3, p4, p5);
    float4 pre[4];
#pragma unroll
    for (int r = 0; r < 4; r++) {
        int i = tid + r * 256;
        pre[r] = (i < (G * 85 / 4)) ? cur.p[i] : make_float4(0.f, 0.f, 0.f, 0.f);
    }
    for (int it = 0; it < CPB; ++it) {
#pragma unroll
        for (int r = 0; r < 4; r++) {
            int i = tid + r * 256;
            if (i < (G * 85 / 4)) ((float4*)buf)[i] = pre[r];
        }
        Chunk nxt = cur;
        if (it + 1 < CPB) {
            nxt = chunk_of(g0 + it + 1, p3, p4, p5);
#pragma unroll
            for (int r = 0; r < 4; r++) {
                int i = tid + r * 256;
                pre[r] = (i < (G * 85 / 4)) ? nxt.p[i] : make_float4(0.f, 0.f, 0.f, 0.f);
            }
        }
        __syncthreads();
        if (tid < 240) {
            int a = tid % G, part = tid / G;
            const float* base = buf + a * 85 + 5 + part * 16;
            float m = base[0];
#pragma unroll
            for (int k = 1; k < 16; k++) m = fmaxf(m, base[k]);
            pmax[part * G + a] = m;
        }
        __syncthreads();
        if (tid < G) {
            float m = pmax[tid];
#pragma unroll
            for (int p = 1; p < 5; p++) m = fmaxf(m, pmax[p * G + tid]);
            float obj = sg(buf[tid * 85 + 4]);
            float v = 0.0f;
            if (obj > SCORE_T) v = obj * sg(m);
            gmax[cur.outbase + tid] = v;
        }
        __syncthreads();
        cur = nxt;
    }
}

union Ovl {
    struct { float tile[TILE * 85]; } p1;
    struct {
        ull msk[KC * 5];
        float4 bx[KC];
        int lab[KC];
        float sc2[KC];
        float ar[KC];
        ull keep[5];
        unsigned int actw[10];
        int wpref[6];
        int order[DET];
        int okept[DET];
    } p2;
};

__global__ __launch_bounds__(1024) void k_img(
    const float* __restrict__ p3, const float* __restrict__ p4, const float* __restrict__ p5,
    const float* __restrict__ anchors, const int* __restrict__ imshapes,
    const float* __restrict__ scalef, const float* __restrict__ gmax,
    float* __restrict__ out) {
    __shared__ unsigned int hist[SBINS];
    __shared__ int alist[CAP];
    __shared__ __align__(16) Ovl u;
    __shared__ float cs[CAP];
    __shared__ unsigned int ci[CAP];
    __shared__ float sv[KC];
    __shared__ unsigned int si[KC];
    __shared__ unsigned int acnt, scnt;
    __shared__ int TaS, TsS;

    int b = blockIdx.x;
    int tid = threadIdx.x;
    const float* gm = gmax + (size_t)b * NANCH;

    hist[tid & (SBINS - 1)] = 0u;
    if (tid == 0) { acnt = 0u; scnt = 0u; TaS = 0; TsS = 0; }
    __syncthreads();
    for (int n = tid; n < NANCH; n += 1024) {
        float v = gm[n];
        if (v > SCORE_T) {
            int bin = (int)((v - SCORE_T) * (ABINS / 0.75f));
            bin = bin < 0 ? 0 : (bin > ABINS - 1 ? ABINS - 1 : bin);
            atomicAdd(&hist[bin], 1u);
        }
    }
    __syncthreads();
    unsigned int run = 0;
    if (tid < ABINS) run = hist[tid];
    __syncthreads();
    for (int off = 1; off < ABINS; off <<= 1) {
        unsigned int add = (tid < ABINS && tid + off < ABINS) ? hist[tid + off] : 0u;
        __syncthreads();
        if (tid < ABINS) { run += add; hist[tid] = run; }
        __syncthreads();
    }
    if (tid < ABINS && run >= KC && (tid == ABINS - 1 || hist[tid + 1] < KC)) TaS = tid;
    __syncthreads();
    int Ta = TaS;

    for (int n = tid; n < NANCH; n += 1024) {
        float v = gm[n];
        if (v > SCORE_T) {
            int bin = (int)((v - SCORE_T) * (ABINS / 0.75f));
            bin = bin < 0 ? 0 : (bin > ABINS - 1 ? ABINS - 1 : bin);
            if (bin >= Ta) {
                unsigned int pos = atomicAdd(&acnt, 1u);
                if (pos < CAP) alist[pos] = n;
            }
        }
    }
    __syncthreads();
    int M = (int)(acnt < CAP ? acnt : CAP);

    hist[tid] = 0u;
    __syncthreads();
    for (int t0 = 0; t0 < M; t0 += TILE) {
        int tc = min(TILE, M - t0);
        for (int idx = tid; idx < tc * 85; idx += 1024) {
            int a = idx / 85, f = idx - a * 85;
            u.p1.tile[idx] = anchor_base(p3, p4, p5, b, alist[t0 + a])[f];
        }
        __syncthreads();
        for (int idx = tid; idx < tc * 80; idx += 1024) {
            int a = idx / 80, c = idx - a * 80;
            float s = sg(u.p1.tile[a * 85 + 4]) * sg(u.p1.tile[a * 85 + 5 + c]);
            if (s > SCORE_T) {
                int bin = (int)((s - SCORE_T) * (SBINS / 0.75f));
                bin = bin < 0 ? 0 : (bin > SBINS - 1 ? SBINS - 1 : bin);
                atomicAdd(&hist[bin], 1u);
            }
        }
        __syncthreads();
    }
    run = hist[tid];
    __syncthreads();
    for (int off = 1; off < SBINS; off <<= 1) {
        unsigned int add = (tid + off < SBINS) ? hist[tid + off] : 0u;
        __syncthreads();
        run += add;
        hist[tid] = run;
        __syncthreads();
    }
    if (run >= KC && (tid == SBINS - 1 || hist[tid + 1] < KC)) TsS = tid;
    __syncthreads();
    int Ts = TsS;

    for (int t0 = 0; t0 < M; t0 += TILE) {
        int tc = min(TILE, M - t0);
        for (int idx = tid; idx < tc * 85; idx += 1024) {
            int a = idx / 85, f = idx - a * 85;
            u.p1.tile[idx] = anchor_base(p3, p4, p5, b, alist[t0 + a])[f];
        }
        __syncthreads();
        for (int idx = tid; idx < tc * 80; idx += 1024) {
            int a = idx / 80, c = idx - a * 80;
            float s = sg(u.p1.tile[a * 85 + 4]) * sg(u.p1.tile[a * 85 + 5 + c]);
            if (s > SCORE_T) {
                int bin = (int)((s - SCORE_T) * (SBINS / 0.75f));
                bin = bin < 0 ? 0 : (bin > SBINS - 1 ? SBINS - 1 : bin);
                if (bin >= Ts) {
                    unsigned int pos = atomicAdd(&scnt, 1u);
                    if (pos < CAP) {
                        cs[pos] = s;
                        ci[pos] = (unsigned int)(alist[t0 + a] * NCLS + c);
                    }
                }
            }
        }
        __syncthreads();
    }
    int nc = (int)(scnt < CAP ? scnt : CAP);

    if (tid < KC) { sv[tid] = 0.f; si[tid] = 0xffffffffu; }
    __syncthreads();
    for (int i = tid; i < nc; i += 1024) {
        float s = cs[i];
        unsigned int ii = ci[i];
        int r = 0;
        for (int j = 0; j < nc; j++) {
            float sj = cs[j];
            unsigned int ij = ci[j];
            if (sj > s || (sj == s && ij < ii)) r++;
        }
        if (r < KC) { sv[r] = s; si[r] = ii; }
    }
    __syncthreads();
    int valid = nc < KC ? nc : KC;

    if (tid < KC) {
        int i = tid;
        if (i < valid) {
            unsigned int fi = si[i];
            int n = (int)(fi / NCLS), c = (int)(fi % NCLS);
            int lvl = (n < 19200) ? 0 : (n < 24000 ? 1 : 2);
            const int offl[3] = {0, 19200, 24000};
            const int Wl[3] = {80, 40, 20};
            const int cntl[3] = {19200, 4800, 1200};
            const float strl[3] = {8.f, 16.f, 32.f};
            const float* pp = lvl == 0 ? p3 : (lvl == 1 ? p4 : p5);
            int nl = n - offl[lvl];
            int a = nl % 3, cell = nl / 3;
            int gx = cell % Wl[lvl], gy = cell / Wl[lvl];
            const float* pb = pp + ((size_t)b * cntl[lvl] + nl) * 85;
            float s0 = sg(pb[0]), s1 = sg(pb[1]), s2 = sg(pb[2]), s3 = sg(pb[3]);
            float stride = strl[lvl];
            float aw = anchors[(lvl * 3 + a) * 2 + 0];
            float ah = anchors[(lvl * 3 + a) * 2 + 1];
            float cx = (2.0f * s0 - 0.5f + (float)gx) * stride;
            float cy = (2.0f * s1 - 0.5f + (float)gy) * stride;
            float bw = 4.0f * s2 * s2 * aw;
            float bh = 4.0f * s3 * s3 * ah;
            float hf = (float)imshapes[b * 2 + 0];
            float wf = (float)imshapes[b * 2 + 1];
            float x1 = cx - bw / 2.0f, y1 = cy - bh / 2.0f;
            float x2 = cx + bw / 2.0f, y2 = cy + bh / 2.0f;
            x1 = fminf(fmaxf(x1, 0.f), wf);
            y1 = fminf(fmaxf(y1, 0.f), hf);
            x2 = fminf(fmaxf(x2, 0.f), wf);
            y2 = fminf(fmaxf(y2, 0.f), hf);
            u.p2.bx[i] = make_float4(x1, y1, x2, y2);
            u.p2.lab[i] = c;
            u.p2.sc2[i] = sv[i];
            u.p2.ar[i] = (x2 - x1) * (y2 - y1);
        } else {
            u.p2.bx[i] = make_float4(0, 0, 0, 0);
            u.p2.lab[i] = -1 - i;
            u.p2.sc2[i] = 0.f;
            u.p2.ar[i] = 0.f;
        }
    }
    __syncthreads();

    if (tid < 10) u.p2.actw[tid] = 0u;
    for (int t = tid; t < KC * 5; t += 1024) {
        int i = t / 5, w = t % 5;
        float4 bi = u.p2.bx[i];
        int li = u.p2.lab[i];
        float ai = u.p2.ar[i];
        ull m = 0ull;
        for (int tb = 0; tb < 64; tb++) {
            int j = w * 64 + tb;
            if (j < KC && j > i && u.p2.lab[j] == li) {
                float4 bj = u.p2.bx[j];
                float ltx = fmaxf(bi.x, bj.x), lty = fmaxf(bi.y, bj.y);
                float rbx = fminf(bi.z, bj.z), rby = fminf(bi.w, bj.w);
                float iw = fmaxf(rbx - ltx, 0.f), ih = fmaxf(rby - lty, 0.f);
                float inter = iw * ih;
                float iou = inter / (ai + u.p2.ar[j] - inter + 1e-9f);
                if (iou > NMS_T) m |= (1ull << tb);
            }
        }
        u.p2.msk[t] = m;
    }
    __syncthreads();

    for (int i = tid; i < KC; i += 1024) {
        ull nz = u.p2.msk[i * 5] | u.p2.msk[i * 5 + 1] | u.p2.msk[i * 5 + 2] |
                 u.p2.msk[i * 5 + 3] | u.p2.msk[i * 5 + 4];
        if (nz) atomicOr(&u.p2.actw[i >> 5], 1u << (i & 31));
    }
    __syncthreads();
    if (tid == 0) {
        u.p2.keep[0] = u.p2.keep[1] = u.p2.keep[2] = u.p2.keep[3] = u.p2.keep[4] = ~0ull;
        for (int w = 0; w < 10; w++) {
            unsigned int mw = u.p2.actw[w];
            while (mw) {
                int bpos = __ffs(mw) - 1;
                mw &= mw - 1;
                int i = w * 32 + bpos;
                if ((u.p2.keep[i >> 6] >> (i & 63)) & 1ull) {
#pragma unroll
                    for (int r = 0; r < 5; r++) u.p2.keep[r] &= ~u.p2.msk[i * 5 + r];
                }
            }
        }
        int s = 0;
        for (int w = 0; w < 5; w++) {
            ull kw = u.p2.keep[w];
            if (w == 4) kw &= (1ull << 44) - 1ull;
            u.p2.wpref[w] = s;
            s += (int)__popcll(kw);
        }
        u.p2.wpref[5] = s;
    }
    __syncthreads();

    if (tid < KC) {
        int w = tid >> 6, bp = tid & 63;
        ull kw = u.p2.keep[w];
        bool kept = (kw >> bp) & 1ull;
        int r = u.p2.wpref[w] + (int)__popcll(kw & ((1ull << bp) - 1ull));
        if (kept) {
            if (r < DET) { u.p2.order[r] = tid; u.p2.okept[r] = 1; }
        } else {
            int nr = u.p2.wpref[5] + (tid - r);
            if (nr < DET) { u.p2.order[nr] = tid; u.p2.okept[nr] = 0; }
        }
    }
    __syncthreads();

    if (tid < DET) {
        int o = u.p2.order[tid];
        float scale = scalef[b];
        float4 bb = u.p2.bx[o];
        float s = (u.p2.okept[tid] && o < valid) ? u.p2.sc2[o] : 0.f;
        float lb = (o < valid) ? (float)u.p2.lab[o] : 0.f;
        float* po = out + ((size_t)b * DET + tid) * 6;
        po[0] = bb.x / scale;
        po[1] = bb.y / scale;
        po[2] = bb.z / scale;
        po[3] = bb.w / scale;
        po[4] = s;
        po[5] = lb;
    }
}

extern "C" void kernel_launch(void* const* d_in, const int* in_sizes, int n_in,
                              void* d_out, int out_size, void* d_ws, size_t ws_size,
                              hipStream_t stream) {
    const float* p3 = (const float*)d_in[0];
    const float* p4 = (const float*)d_in[1];
    const float* p5 = (const float*)d_in[2];
    const float* anchors = (const float*)d_in[3];
    const int* imshapes = (const int*)d_in[4];
    const float* scalef = (const float*)d_in[5];
    float* out = (float*)d_out;

    // workspace layout — shist, acnt, scnt contiguous (zeroed in one loop in P1)
    float* gmax = (float*)d_ws;                                // 16*25200 f32
    uint2* cand = (uint2*)(gmax + BATCH * NANCH);              // 16*2048 uint2
    unsigned int* shist = (unsigned int*)(cand + BATCH * CAP); // 16*1024
    unsigned int* acnt = shist + BATCH * SBINS;                // 16
    unsigned int* scnt = acnt + BATCH;                         // 16
    int* alist = (int*)(scnt + BATCH);                         // 16*2048

    void* args[] = {(void*)&p3, (void*)&p4, (void*)&p5, (void*)&anchors,
                    (void*)&imshapes, (void*)&scalef, (void*)&gmax, (void*)&shist,
                    (void*)&acnt, (void*)&scnt, (void*)&alist, (void*)&cand, (void*)&out};
    hipError_t err = hipLaunchCooperativeKernel((const void*)k_all, dim3(NBLK), dim3(NTHR),
                                                args, 0, stream);
    if (err != hipSuccess) {
        // fallback: proven two-kernel path (R6)
        k_max<<<TOTCH / CPB, 256, 0, stream>>>(p3, p4, p5, gmax);
        k_img<<<BATCH, 1024, 0, stream>>>(p3, p4, p5, anchors, imshapes, scalef, gmax, out);
    }
}